// Round 6
// baseline (60.285 us; speedup 1.0000x reference)
//
#include <hip/hip_runtime.h>
#include <math.h>

#define W48 48
#define HD 2304
#define WHD 110592
#define NR 32
#define NB 8
#define QPP 27648            // float4 groups per (b,r) plane
#define TPB 64               // ONE wave per block
#define CHUNKS 432           // QPP / 64
#define MAIN_BLOCKS 3456     // NB * CHUNKS
#define NTOT 28311552.0

struct PPart { float s0, sx, sy, mv; unsigned idx; }; // 20 B

// ws layout (bytes)
#define PP_OFF   0u
#define BLK_OFF  2211840u            // 110592 * 20
#define PD_OFF   2350080u            // + 3456*5*8
#define DP_OFF   2352128u            // + 256*8
#define CNT_OFF  2362368u            // + 256*5*8

// ------------- fused single-pass kernel: 1 wave/block, LDS-deferred per-r reduce -------------
__global__ __launch_bounds__(64, 4)
void k_main(const float* __restrict__ feat, PPart* __restrict__ pp,
            double* __restrict__ blk) {
  __shared__ float lds_s0[16 * 64];    // 4 KB [r16][t]
  __shared__ float lds_mv[16 * 64];    // 4 KB [r16][t]
  __shared__ float lds_fi[64], lds_fj[64];
  __shared__ unsigned lds_mc[64];

  const int bid = blockIdx.x;
  const int t = threadIdx.x;
  const int b = bid / CHUNKS;
  const int chunk = bid - b * CHUNKS;
  const int qbase = chunk * 64 + t;
  const float4* gptr = reinterpret_cast<const float4*>(feat) + (size_t)b * (NR * QPP) + qbase;

  const int p0 = qbase * 4;
  const float fi = (float)(p0 / HD);
  const float fj = (float)((p0 / W48) % W48);   // constant over the 4 elems (4 | 48)
  const float rrq = fi * fi + fj * fj;
  lds_fi[t] = fi; lds_fj[t] = fj;

  float v1[4], v2[4], cp[4];
#pragma unroll
  for (int c = 0; c < 4; ++c) { v1[c] = -INFINITY; v2[c] = -INFINITY; cp[c] = 0.f; }
  float ssum = 0.f, sii = 0.f;
  unsigned mcpack = 0u;

  float4 nb0 = gptr[0];
  float4 nb1 = gptr[(size_t)QPP];
  float4 nb2 = gptr[2 * (size_t)QPP];
  float4 nb3 = gptr[3 * (size_t)QPP];

  for (int half = 0; half < 2; ++half) {
#pragma unroll 4
    for (int rr = 0; rr < 16; ++rr) {
      const int r = half * 16 + rr;
      float4 v = nb0; nb0 = nb1; nb1 = nb2; nb2 = nb3;
      int rn = r + 4; rn = (rn < NR) ? rn : (NR - 1);     // clamped redundant tail load
      nb3 = gptr[(size_t)rn * QPP];

      float vv[4] = {v.x, v.y, v.z, v.w};
      float f2[4];
#pragma unroll
      for (int c = 0; c < 4; ++c) {
        float f = vv[c];
        f2[c] = f * f;
        cp[c] += f2[c];
        float nv2 = fmaxf(f, v2[c]);
        v2[c] = (f > v1[c]) ? v1[c] : nv2;     // top-2 insert (first-index semantics)
        v1[c] = fmaxf(v1[c], f);
      }
      ssum += (vv[0] + vv[1]) + (vv[2] + vv[3]);
      float s0t = (f2[0] + f2[1]) + (f2[2] + f2[3]);
      sii += s0t * rrq;

      float mv = fmaxf(fmaxf(vv[0], vv[1]), fmaxf(vv[2], vv[3]));
      int mc = (mv == vv[0]) ? 0 : ((mv == vv[1]) ? 1 : ((mv == vv[2]) ? 2 : 3)); // first idx
      mcpack |= (unsigned)mc << (2 * rr);
      lds_s0[rr * 64 + t] = s0t;
      lds_mv[rr * 64 + t] = mv;
    }

    // ---- epilogue: transpose-reduce the 16 r's in parallel (16 er × 4 eg) ----
    lds_mc[t] = mcpack; mcpack = 0u;
    __syncthreads();                       // 1-wave: cheap; orders LDS writes/reads
    const int er = t & 15;                 // which r this thread reduces
    const int eg = t >> 4;                 // which quarter of the 64 rows
    float es0 = 0.f, esx = 0.f, esy = 0.f;
    float bmv = -INFINITY; int brow = 0;
#pragma unroll
    for (int k = 0; k < 16; ++k) {
      int row = eg * 16 + ((k + er) & 15);     // rotation: 2-way bank alias only (free)
      float s0v = lds_s0[er * 64 + row];
      float mvv = lds_mv[er * 64 + row];
      es0 += s0v;
      esx = fmaf(s0v, lds_fi[row], esx);
      esy = fmaf(s0v, lds_fj[row], esy);
      if (mvv > bmv || (mvv == bmv && row < brow)) { bmv = mvv; brow = row; }
    }
    unsigned bidx = (unsigned)((chunk * 64 + brow) * 4) + ((lds_mc[brow] >> (2 * er)) & 3u);

    // combine the 4 eg-partials per er: lanes {er, er+16, er+32, er+48}
#pragma unroll
    for (int m = 16; m <= 32; m <<= 1) {
      es0 += __shfl_xor(es0, m);
      esx += __shfl_xor(esx, m);
      esy += __shfl_xor(esy, m);
      float omv = __shfl_xor(bmv, m);
      unsigned oix = (unsigned)__shfl_xor((int)bidx, m);
      if (omv > bmv || (omv == bmv && oix < bidx)) { bmv = omv; bidx = oix; }
    }
    if (t < 16) {
      int plane = b * NR + half * 16 + er;
      PPart o; o.s0 = es0; o.sx = esx; o.sy = esy; o.mv = bmv; o.idx = bidx;
      pp[(size_t)plane * CHUNKS + chunk] = o;
    }
    __syncthreads();                       // arena reuse for next half
  }

  // ---- div epilogue (f2@argmax == v1^2) + global sums, single-wave reduce ----
  float A = 0.f, Bs = 0.f, C = 0.f;
#pragma unroll
  for (int c = 0; c < 4; ++c) {
    float m1 = v1[c], m1sq = m1 * m1;
    float rest = cp[c] - m1sq;
    A  += m1sq * rest + v2[c] * v2[c] * m1sq;
    Bs += m1 * rest + v2[c] * m1sq;
    C  += cp[c];
  }
  double dA = A, dB = Bs, dC = C, dS = ssum, dI = sii;
#pragma unroll
  for (int off = 32; off; off >>= 1) {
    dA += __shfl_down(dA, off);
    dB += __shfl_down(dB, off);
    dC += __shfl_down(dC, off);
    dS += __shfl_down(dS, off);
    dI += __shfl_down(dI, off);
  }
  if (t == 0) {
    blk[(size_t)bid * 5 + 0] = dA;
    blk[(size_t)bid * 5 + 1] = dB;
    blk[(size_t)bid * 5 + 2] = dC;
    blk[(size_t)bid * 5 + 3] = dS;
    blk[(size_t)bid * 5 + 4] = dI;
  }
}

// ------------- fused finalize: per-plane combine + last-block final scalars -------------
__global__ __launch_bounds__(512)
void k_reduce(const PPart* __restrict__ pp, const double* __restrict__ blk,
              double* __restrict__ planeDis, double* __restrict__ divpart,
              unsigned* __restrict__ counter, float* __restrict__ out) {
  __shared__ double ls[8][3];
  __shared__ float lmv8[8];
  __shared__ unsigned lidx8[8];
  __shared__ double fin[8][6];
  __shared__ int lastFlag;

  const int p = blockIdx.x;               // 256 blocks = one per plane
  const int t = threadIdx.x;
  const int wave = t >> 6, lane = t & 63;

  // ---- part 1: combine 432 chunk-partials of plane p ----
  double s0 = 0, sx = 0, sy = 0;
  float mv = -INFINITY; unsigned idx = 0xffffffffu;
  if (t < CHUNKS) {
    PPart v = pp[(size_t)p * CHUNKS + t];
    s0 = v.s0; sx = v.sx; sy = v.sy; mv = v.mv; idx = v.idx;
  }
#pragma unroll
  for (int off = 32; off; off >>= 1) {
    s0 += __shfl_down(s0, off);
    sx += __shfl_down(sx, off);
    sy += __shfl_down(sy, off);
    float omv = __shfl_down(mv, off);
    unsigned oix = (unsigned)__shfl_down((int)idx, off);
    if (omv > mv || (omv == mv && oix < idx)) { mv = omv; idx = oix; }
  }
  if (lane == 0) { ls[wave][0] = s0; ls[wave][1] = sx; ls[wave][2] = sy; lmv8[wave] = mv; lidx8[wave] = idx; }
  __syncthreads();
  if (t == 0) {
    double a0 = 0, a1 = 0, a2 = 0; float bm = -INFINITY; unsigned bi = 0xffffffffu;
#pragma unroll
    for (int w = 0; w < 8; ++w) {
      a0 += ls[w][0]; a1 += ls[w][1]; a2 += ls[w][2];
      if (lmv8[w] > bm || (lmv8[w] == bm && lidx8[w] < bi)) { bm = lmv8[w]; bi = lidx8[w]; }
    }
    int am = (int)bi;
    int mx = am / HD;
    int rem = am - mx * HD;
    int my = rem / W48;
    int mz = rem - my * W48;
    double dmx = mx, dmy = my, dmz = mz;
    // sum_k (mz-k)^2, k=0..47 = 48 mz^2 - 2256 mz + 35720 ; times W*H=2304
    planeDis[p] = (dmx*dmx + dmy*dmy) * a0 - 2.0*dmx*a1 - 2.0*dmy*a2
                + 2304.0 * (48.0*dmz*dmz - 2256.0*dmz + 35720.0);
  }

  // ---- part 2: this block's slice of the div/global sums (rows p, p+256, ...) ----
  double A = 0, Bs = 0, C = 0, S = 0, SI = 0;
  if (t < 16) {
    int i = p + 256 * t;
    if (i < MAIN_BLOCKS) {
      const double* bb = blk + (size_t)i * 5;
      A = bb[0]; Bs = bb[1]; C = bb[2]; S = bb[3]; SI = bb[4];
    }
  }
#pragma unroll
  for (int off = 8; off; off >>= 1) {
    A  += __shfl_down(A, off);
    Bs += __shfl_down(Bs, off);
    C  += __shfl_down(C, off);
    S  += __shfl_down(S, off);
    SI += __shfl_down(SI, off);
  }
  if (t == 0) {
    double* dp = divpart + (size_t)p * 5;
    dp[0] = A; dp[1] = Bs; dp[2] = C; dp[3] = S; dp[4] = SI;
  }
  __syncthreads();

  // ---- last-block final reduction ----
  if (t == 0) {
    __threadfence();                              // release planeDis/divpart
    unsigned old = atomicAdd(counter, 1u);        // device-scope
    lastFlag = (old == 255u);
  }
  __syncthreads();
  if (lastFlag) {
    __threadfence();                              // acquire other blocks' writes
    double dis = 0, fA = 0, fB = 0, fC = 0, fS = 0, fI = 0;
    if (t < 256) {
      dis = planeDis[t];
      const double* dp = divpart + (size_t)t * 5;
      fA = dp[0]; fB = dp[1]; fC = dp[2]; fS = dp[3]; fI = dp[4];
    }
#pragma unroll
    for (int off = 32; off; off >>= 1) {
      dis += __shfl_down(dis, off);
      fA  += __shfl_down(fA, off);
      fB  += __shfl_down(fB, off);
      fC  += __shfl_down(fC, off);
      fS  += __shfl_down(fS, off);
      fI  += __shfl_down(fI, off);
    }
    if (lane == 0) {
      fin[wave][0] = dis; fin[wave][1] = fA; fin[wave][2] = fB;
      fin[wave][3] = fC;  fin[wave][4] = fS; fin[wave][5] = fI;
    }
    __syncthreads();
    if (t == 0) {
      double td = 0, tA = 0, tB = 0, tC = 0, tS = 0, tI = 0;
#pragma unroll
      for (int w = 0; w < 8; ++w) {
        td += fin[w][0]; tA += fin[w][1]; tB += fin[w][2];
        tC += fin[w][3]; tS += fin[w][4]; tI += fin[w][5];
      }
      double mgr = tS / NTOT;
      out[0] = (float)((td + tI) / NTOT);
      out[1] = (float)((tA - 2.0*mgr*tB + mgr*mgr*tC) / NTOT);
    }
  }
}

extern "C" void kernel_launch(void* const* d_in, const int* in_sizes, int n_in,
                              void* d_out, int out_size, void* d_ws, size_t ws_size,
                              hipStream_t stream) {
  // inputs: [0]=backbone_feature (unused), [1]=grouping_result (unused), [2]=feature
  const float* feat = (const float*)d_in[2];
  float* out = (float*)d_out;

  PPart* pp        = (PPart*)((char*)d_ws + PP_OFF);
  double* blk      = (double*)((char*)d_ws + BLK_OFF);
  double* planeDis = (double*)((char*)d_ws + PD_OFF);
  double* divpart  = (double*)((char*)d_ws + DP_OFF);
  unsigned* cnt    = (unsigned*)((char*)d_ws + CNT_OFF);

  hipMemsetAsync(cnt, 0, 4, stream);              // reset last-block counter each launch
  k_main<<<MAIN_BLOCKS, TPB, 0, stream>>>(feat, pp, blk);
  k_reduce<<<256, 512, 0, stream>>>(pp, blk, planeDis, divpart, cnt, out);
}